// Round 6
// baseline (819.945 us; speedup 1.0000x reference)
//
#include <hip/hip_runtime.h>

// LSTM: B=2048, T=512, I=1, H=64, L=2, O=1. fp32 in/out.
// Round 6: gate-aligned MFMA columns + in-register combine.
// r5 was phase-sum bound: pD LDS round-trip (~800 cyc/step) + 2 barriers.
// Now wave w owns hidden units j in [8w,8w+8) x all 4 gates (32 cols:
// tile0 = i|f, tile1 = g|o). After MFMA, gates for (j,b) live in lane pair
// (L, L^8): one DPP row_ror:8 exchange (VALU pipe!) + selects -> full
// combine in registers. h scattered directly into double-buffered A-frag
// LDS; ONE barrier/step. Layer skew kept: iter k computes
//   G1 = Whh0*h1(k-1), G2 = Wih1*h1(k-1) + Whh1*h2(k-2)
// -> combine h1(k), h2(k-1) -> scatter to buf p^1.
//   - 256 blocks x 512 threads (8 waves, 2/SIMD), BT=8.
//   - fp32 accuracy via bf16 hi+lo 3-product split.

#define TT 512
#define HH 64
#define BT 8

typedef __attribute__((ext_vector_type(8))) short short8;
typedef __attribute__((ext_vector_type(4))) float f32x4;

#define MFMA16 __builtin_amdgcn_mfma_f32_16x16x32_bf16

__device__ __forceinline__ float sigm(float x) {
    return __builtin_amdgcn_rcpf(1.f + __expf(-x));
}
__device__ __forceinline__ float tanh_f(float x) {
    float xc = fminf(fmaxf(x, -15.f), 15.f);
    float e = __expf(2.f * xc);
    return (e - 1.f) * __builtin_amdgcn_rcpf(e + 1.f);
}
__device__ __forceinline__ void cvt8(const float* p, short8& hi, short8& lo) {
    #pragma unroll
    for (int i = 0; i < 8; ++i) {
        float v = p[i];
        unsigned short h = (unsigned short)(__float_as_uint(v) >> 16);
        float r = v - __uint_as_float(((unsigned)h) << 16);
        unsigned short l = (unsigned short)(__float_as_uint(r) >> 16);
        hi[i] = (short)h;
        lo[i] = (short)l;
    }
}
__device__ __forceinline__ void split1(float v, unsigned short& h, unsigned short& l) {
    h = (unsigned short)(__float_as_uint(v) >> 16);
    float r = v - __uint_as_float(((unsigned)h) << 16);
    l = (unsigned short)(__float_as_uint(r) >> 16);
}
// lane <-> lane^8 exchange on the VALU pipe (DPP row_ror:8, rows of 16)
__device__ __forceinline__ float dppx8(float v) {
    return __int_as_float(__builtin_amdgcn_update_dpp(
        0, __float_as_int(v), 0x128, 0xF, 0xF, true));
}

__global__ __launch_bounds__(512, 2) void lstm_mfma(
    const float* __restrict__ x,
    const float* __restrict__ Wih0, const float* __restrict__ Whh0,
    const float* __restrict__ bih0, const float* __restrict__ bhh0,
    const float* __restrict__ Wih1, const float* __restrict__ Whh1,
    const float* __restrict__ bih1, const float* __restrict__ bhh1,
    const float* __restrict__ fcW, const float* __restrict__ fcb,
    float* __restrict__ out)
{
    __shared__ float xs[BT][TT + 1];                     // 16.4 KB
    __shared__ __align__(16) short aH1[2][2][2][64][8];  // 8 KB [buf][kt][hi/lo][lane][e]
    __shared__ __align__(16) short aH2[2][2][2][64][8];  // 8 KB
    __shared__ float hF[BT][HH + 1];
    __shared__ float fcw_s[HH];

    const int t    = threadIdx.x;
    const int lane = t & 63;
    const int w    = t >> 6;        // wave 0..7: owns hidden units [8w, 8w+8)
    const int b0   = blockIdx.x * BT;

    // ---- stage x (coalesced rows); zero both A-frag buffers ----
    for (int i = t; i < BT * TT; i += 512)
        xs[i >> 9][i & (TT - 1)] = x[(size_t)(b0 + (i >> 9)) * TT + (i & (TT - 1))];
    {
        int* z1 = (int*)aH1;
        for (int i = t; i < 2048; i += 512) z1[i] = 0;
        int* z2 = (int*)aH2;
        for (int i = t; i < 2048; i += 512) z2[i] = 0;
    }
    if (t < HH) fcw_s[t] = fcW[t];

    // ---- persistent B fragments, gate-aligned columns ----
    // tile nt: gate g = 2*nt + (n_lo>>3), hidden j = 8w + (n_lo&7)
    short8 bh0[2][2], bl0[2][2], bhI[2][2], blI[2][2], bhH[2][2], blH[2][2];
    {
        const int n_lo = lane & 15;
        const int k8   = (lane >> 4) * 8;
        const int jjn  = n_lo & 7;
        #pragma unroll
        for (int nt = 0; nt < 2; ++nt) {
            const int g = nt * 2 + (n_lo >> 3);
            const int r = g * 64 + 8 * w + jjn;
            #pragma unroll
            for (int kt = 0; kt < 2; ++kt) {
                cvt8(Whh0 + r * HH + kt * 32 + k8, bh0[kt][nt], bl0[kt][nt]);
                cvt8(Wih1 + r * HH + kt * 32 + k8, bhI[kt][nt], blI[kt][nt]);
                cvt8(Whh1 + r * HH + kt * 32 + k8, bhH[kt][nt], blH[kt][nt]);
            }
        }
    }

    // ---- combine-lane constants ----
    const int jj   = lane & 7;
    const int jmy  = 8 * w + jj;          // my hidden unit
    const int quad = lane >> 4;           // 0,1 real (m 0..7); 2,3 junk
    const int isB  = (lane >> 3) & 1;     // 0: batches {q*4+0,1}, 1: {q*4+2,3}
    const int mb0  = quad * 4 + isB * 2;
    const int mb1  = mb0 + 1;
    const int mc0  = mb0 & 7, mc1 = mb1 & 7;   // clamped for safe xs reads
    const bool wr  = (quad < 2);
    const int ktu  = w >> 2;              // A-frag kt of my j (wave-uniform)
    const int rowu = (w & 3) * 16;        // A-frag row base of my j

    const float wxi = Wih0[jmy],       wxf = Wih0[64 + jmy],
                wxg = Wih0[128 + jmy], wxo = Wih0[192 + jmy];
    const float b1i = bih0[jmy] + bhh0[jmy],             b1f = bih0[64 + jmy] + bhh0[64 + jmy];
    const float b1g = bih0[128 + jmy] + bhh0[128 + jmy], b1o = bih0[192 + jmy] + bhh0[192 + jmy];
    const float b2i = bih1[jmy] + bhh1[jmy],             b2f = bih1[64 + jmy] + bhh1[64 + jmy];
    const float b2g = bih1[128 + jmy] + bhh1[128 + jmy], b2o = bih1[192 + jmy] + bhh1[192 + jmy];

    float c1a = 0.f, c1b = 0.f, c2a = 0.f, c2b = 0.f;
    __syncthreads();

    #pragma unroll 2
    for (int k = 0; k < TT; ++k) {
        const int p = k & 1, pn = p ^ 1;

        // ---- A-frag loads (8 ds_read_b128/wave) ----
        short8 a1h0 = *(const short8*)&aH1[p][0][0][lane][0];
        short8 a1l0 = *(const short8*)&aH1[p][0][1][lane][0];
        short8 a1h1 = *(const short8*)&aH1[p][1][0][lane][0];
        short8 a1l1 = *(const short8*)&aH1[p][1][1][lane][0];
        short8 a2h0 = *(const short8*)&aH2[p][0][0][lane][0];
        short8 a2l0 = *(const short8*)&aH2[p][0][1][lane][0];
        short8 a2h1 = *(const short8*)&aH2[p][1][0][lane][0];
        short8 a2l1 = *(const short8*)&aH2[p][1][1][lane][0];

        const f32x4 z = {0.f, 0.f, 0.f, 0.f};
        // ---- G1 = Whh0 * h1(k-1): tile0 -> i|f, tile1 -> g|o ----
        f32x4 x0 = z, y0 = z, x1 = z, y1 = z;
        x0 = MFMA16(a1h0, bh0[0][0], x0, 0, 0, 0);
        y0 = MFMA16(a1h0, bl0[0][0], y0, 0, 0, 0);
        y0 = MFMA16(a1l0, bh0[0][0], y0, 0, 0, 0);
        x1 = MFMA16(a1h0, bh0[0][1], x1, 0, 0, 0);
        y1 = MFMA16(a1h0, bl0[0][1], y1, 0, 0, 0);
        y1 = MFMA16(a1l0, bh0[0][1], y1, 0, 0, 0);
        x0 = MFMA16(a1h1, bh0[1][0], x0, 0, 0, 0);
        y0 = MFMA16(a1h1, bl0[1][0], y0, 0, 0, 0);
        y0 = MFMA16(a1l1, bh0[1][0], y0, 0, 0, 0);
        x1 = MFMA16(a1h1, bh0[1][1], x1, 0, 0, 0);
        y1 = MFMA16(a1h1, bl0[1][1], y1, 0, 0, 0);
        y1 = MFMA16(a1l1, bh0[1][1], y1, 0, 0, 0);
        f32x4 d0 = x0 + y0, d1 = x1 + y1;

        // ---- G2 = Wih1 * h1(k-1) + Whh1 * h2(k-2) ----
        f32x4 u0 = z, v0 = z, u1 = z, v1 = z;
        u0 = MFMA16(a1h0, bhI[0][0], u0, 0, 0, 0);
        v0 = MFMA16(a1h0, blI[0][0], v0, 0, 0, 0);
        v0 = MFMA16(a1l0, bhI[0][0], v0, 0, 0, 0);
        u0 = MFMA16(a2h0, bhH[0][0], u0, 0, 0, 0);
        v0 = MFMA16(a2h0, blH[0][0], v0, 0, 0, 0);
        v0 = MFMA16(a2l0, bhH[0][0], v0, 0, 0, 0);
        u1 = MFMA16(a1h0, bhI[0][1], u1, 0, 0, 0);
        v1 = MFMA16(a1h0, blI[0][1], v1, 0, 0, 0);
        v1 = MFMA16(a1l0, bhI[0][1], v1, 0, 0, 0);
        u1 = MFMA16(a2h0, bhH[0][1], u1, 0, 0, 0);
        v1 = MFMA16(a2h0, blH[0][1], v1, 0, 0, 0);
        v1 = MFMA16(a2l0, bhH[0][1], v1, 0, 0, 0);
        u0 = MFMA16(a1h1, bhI[1][0], u0, 0, 0, 0);
        v0 = MFMA16(a1h1, blI[1][0], v0, 0, 0, 0);
        v0 = MFMA16(a1l1, bhI[1][0], v0, 0, 0, 0);
        u0 = MFMA16(a2h1, bhH[1][0], u0, 0, 0, 0);
        v0 = MFMA16(a2h1, blH[1][0], v0, 0, 0, 0);
        v0 = MFMA16(a2l1, bhH[1][0], v0, 0, 0, 0);
        u1 = MFMA16(a1h1, bhI[1][1], u1, 0, 0, 0);
        v1 = MFMA16(a1h1, blI[1][1], v1, 0, 0, 0);
        v1 = MFMA16(a1l1, bhI[1][1], v1, 0, 0, 0);
        u1 = MFMA16(a2h1, bhH[1][1], u1, 0, 0, 0);
        v1 = MFMA16(a2h1, blH[1][1], v1, 0, 0, 0);
        v1 = MFMA16(a2l1, bhH[1][1], v1, 0, 0, 0);
        f32x4 e0 = u0 + v0, e1 = u1 + v1;

        // ---- lane^8 exchange (VALU DPP) ----
        f32x4 sd0, sd1, se0, se1;
        #pragma unroll
        for (int r = 0; r < 4; ++r) {
            sd0[r] = dppx8(d0[r]);
            sd1[r] = dppx8(d1[r]);
            se0[r] = dppx8(e0[r]);
            se1[r] = dppx8(e1[r]);
        }

        // ---- my L1 gates for my 2 batches ----
        float gI0 = isB ? sd0[2] : d0[0], gI1 = isB ? sd0[3] : d0[1];
        float gF0 = isB ? d0[2] : sd0[0], gF1 = isB ? d0[3] : sd0[1];
        float gG0 = isB ? sd1[2] : d1[0], gG1 = isB ? sd1[3] : d1[1];
        float gO0 = isB ? d1[2] : sd1[0], gO1 = isB ? d1[3] : sd1[1];

        float xb0 = xs[mc0][k], xb1 = xs[mc1][k];

        // ---- L1 combine -> h1(k) ----
        float i0 = sigm(gI0 + fmaf(wxi, xb0, b1i));
        float f0 = sigm(gF0 + fmaf(wxf, xb0, b1f));
        float g0 = tanh_f(gG0 + fmaf(wxg, xb0, b1g));
        float o0 = sigm(gO0 + fmaf(wxo, xb0, b1o));
        c1a = fmaf(f0, c1a, i0 * g0);
        float h1a = o0 * tanh_f(c1a);
        float i1 = sigm(gI1 + fmaf(wxi, xb1, b1i));
        float f1 = sigm(gF1 + fmaf(wxf, xb1, b1f));
        float g1 = tanh_f(gG1 + fmaf(wxg, xb1, b1g));
        float o1 = sigm(gO1 + fmaf(wxo, xb1, b1o));
        c1b = fmaf(f1, c1b, i1 * g1);
        float h1b = o1 * tanh_f(c1b);

        unsigned short hah, hal, hbh, hbl;
        split1(h1a, hah, hal);
        split1(h1b, hbh, hbl);
        if (wr) {
            aH1[pn][ktu][0][rowu + mb0][jj] = (short)hah;
            aH1[pn][ktu][1][rowu + mb0][jj] = (short)hal;
            aH1[pn][ktu][0][rowu + mb1][jj] = (short)hbh;
            aH1[pn][ktu][1][rowu + mb1][jj] = (short)hbl;
        }

        // ---- L2 combine -> h2(k-1) (skip at k==0) ----
        if (k > 0) {
            float qI0 = isB ? se0[2] : e0[0], qI1 = isB ? se0[3] : e0[1];
            float qF0 = isB ? e0[2] : se0[0], qF1 = isB ? e0[3] : se0[1];
            float qG0 = isB ? se1[2] : e1[0], qG1 = isB ? se1[3] : e1[1];
            float qO0 = isB ? e1[2] : se1[0], qO1 = isB ? e1[3] : se1[1];
            float I0 = sigm(qI0 + b2i);
            float F0 = sigm(qF0 + b2f);
            float G0 = tanh_f(qG0 + b2g);
            float O0 = sigm(qO0 + b2o);
            c2a = fmaf(F0, c2a, I0 * G0);
            float h2a = O0 * tanh_f(c2a);
            float I1 = sigm(qI1 + b2i);
            float F1 = sigm(qF1 + b2f);
            float G1 = tanh_f(qG1 + b2g);
            float O1 = sigm(qO1 + b2o);
            c2b = fmaf(F1, c2b, I1 * G1);
            float h2b = O1 * tanh_f(c2b);

            unsigned short uah, ual, ubh, ubl;
            split1(h2a, uah, ual);
            split1(h2b, ubh, ubl);
            if (wr) {
                aH2[pn][ktu][0][rowu + mb0][jj] = (short)uah;
                aH2[pn][ktu][1][rowu + mb0][jj] = (short)ual;
                aH2[pn][ktu][0][rowu + mb1][jj] = (short)ubh;
                aH2[pn][ktu][1][rowu + mb1][jj] = (short)ubl;
            }
        }
        __syncthreads();
    }

    // ---- epilogue: h2(TT-1) from buf 0 (TT even) ----
    {
        short8 a1h0 = *(const short8*)&aH1[0][0][0][lane][0];
        short8 a1l0 = *(const short8*)&aH1[0][0][1][lane][0];
        short8 a1h1 = *(const short8*)&aH1[0][1][0][lane][0];
        short8 a1l1 = *(const short8*)&aH1[0][1][1][lane][0];
        short8 a2h0 = *(const short8*)&aH2[0][0][0][lane][0];
        short8 a2l0 = *(const short8*)&aH2[0][0][1][lane][0];
        short8 a2h1 = *(const short8*)&aH2[0][1][0][lane][0];
        short8 a2l1 = *(const short8*)&aH2[0][1][1][lane][0];
        const f32x4 z = {0.f, 0.f, 0.f, 0.f};
        f32x4 u0 = z, v0 = z, u1 = z, v1 = z;
        u0 = MFMA16(a1h0, bhI[0][0], u0, 0, 0, 0);
        v0 = MFMA16(a1h0, blI[0][0], v0, 0, 0, 0);
        v0 = MFMA16(a1l0, bhI[0][0], v0, 0, 0, 0);
        u0 = MFMA16(a2h0, bhH[0][0], u0, 0, 0, 0);
        v0 = MFMA16(a2h0, blH[0][0], v0, 0, 0, 0);
        v0 = MFMA16(a2l0, bhH[0][0], v0, 0, 0, 0);
        u1 = MFMA16(a1h0, bhI[0][1], u1, 0, 0, 0);
        v1 = MFMA16(a1h0, blI[0][1], v1, 0, 0, 0);
        v1 = MFMA16(a1l0, bhI[0][1], v1, 0, 0, 0);
        u1 = MFMA16(a2h0, bhH[0][1], u1, 0, 0, 0);
        v1 = MFMA16(a2h0, blH[0][1], v1, 0, 0, 0);
        v1 = MFMA16(a2l0, bhH[0][1], v1, 0, 0, 0);
        u0 = MFMA16(a1h1, bhI[1][0], u0, 0, 0, 0);
        v0 = MFMA16(a1h1, blI[1][0], v0, 0, 0, 0);
        v0 = MFMA16(a1l1, bhI[1][0], v0, 0, 0, 0);
        u0 = MFMA16(a2h1, bhH[1][0], u0, 0, 0, 0);
        v0 = MFMA16(a2h1, blH[1][0], v0, 0, 0, 0);
        v0 = MFMA16(a2l1, bhH[1][0], v0, 0, 0, 0);
        u1 = MFMA16(a1h1, bhI[1][1], u1, 0, 0, 0);
        v1 = MFMA16(a1h1, blI[1][1], v1, 0, 0, 0);
        v1 = MFMA16(a1l1, bhI[1][1], v1, 0, 0, 0);
        u1 = MFMA16(a2h1, bhH[1][1], u1, 0, 0, 0);
        v1 = MFMA16(a2h1, blH[1][1], v1, 0, 0, 0);
        v1 = MFMA16(a2l1, bhH[1][1], v1, 0, 0, 0);
        f32x4 e0 = u0 + v0, e1 = u1 + v1;

        f32x4 se0, se1;
        #pragma unroll
        for (int r = 0; r < 4; ++r) {
            se0[r] = dppx8(e0[r]);
            se1[r] = dppx8(e1[r]);
        }
        float qI0 = isB ? se0[2] : e0[0], qI1 = isB ? se0[3] : e0[1];
        float qF0 = isB ? e0[2] : se0[0], qF1 = isB ? e0[3] : se0[1];
        float qG0 = isB ? se1[2] : e1[0], qG1 = isB ? se1[3] : e1[1];
        float qO0 = isB ? e1[2] : se1[0], qO1 = isB ? e1[3] : se1[1];
        float I0 = sigm(qI0 + b2i);
        float F0 = sigm(qF0 + b2f);
        float G0 = tanh_f(qG0 + b2g);
        float O0 = sigm(qO0 + b2o);
        c2a = fmaf(F0, c2a, I0 * G0);
        float h2a = O0 * tanh_f(c2a);
        float I1 = sigm(qI1 + b2i);
        float F1 = sigm(qF1 + b2f);
        float G1 = tanh_f(qG1 + b2g);
        float O1 = sigm(qO1 + b2o);
        c2b = fmaf(F1, c2b, I1 * G1);
        float h2b = O1 * tanh_f(c2b);
        if (wr) {
            hF[mb0][jmy] = h2a;
            hF[mb1][jmy] = h2b;
        }
    }
    __syncthreads();

    // ---- final FC: out[b] = fcW . h2(TT-1)[b] + fcb ----
    if (t < BT) {
        float s = fcb[0];
        #pragma unroll 8
        for (int j = 0; j < HH; ++j)
            s = fmaf(hF[t][j], fcw_s[j], s);
        out[b0 + t] = s;
    }
}

extern "C" void kernel_launch(void* const* d_in, const int* in_sizes, int n_in,
                              void* d_out, int out_size, void* d_ws, size_t ws_size,
                              hipStream_t stream) {
    const float* x    = (const float*)d_in[0];
    const float* Wih0 = (const float*)d_in[1];
    const float* Whh0 = (const float*)d_in[2];
    const float* bih0 = (const float*)d_in[3];
    const float* bhh0 = (const float*)d_in[4];
    const float* Wih1 = (const float*)d_in[5];
    const float* Whh1 = (const float*)d_in[6];
    const float* bih1 = (const float*)d_in[7];
    const float* bhh1 = (const float*)d_in[8];
    const float* fcW  = (const float*)d_in[9];
    const float* fcb  = (const float*)d_in[10];
    float* out = (float*)d_out;

    lstm_mfma<<<dim3(2048 / BT), dim3(512), 0, stream>>>(
        x, Wih0, Whh0, bih0, bhh0, Wih1, Whh1, bih1, bhh1, fcW, fcb, out);
}

// Round 7
// 584.433 us; speedup vs baseline: 1.4030x; 1.4030x over previous
//
#include <hip/hip_runtime.h>

// LSTM: B=2048, T=512, I=1, H=64, L=2, O=1. fp32 in/out.
// Round 7: wave-group specialization (r5 structure + phase overlap).
// r5 was phase-sum bound (all waves MFMA, then all combine -> pipes idle
// alternately). r6's in-register combine bloated VALU 2x. Now:
//   waves 0-3 (L1-group): own all 256 G1 cols (64/wave, 4 N-tiles)
//   waves 4-7 (L2-group): own all 256 G2 cols
// Skewed per step k:
//   phase A: L1 MFMA G1(k)->pD1          | L2 combine h2(k-2)<-pD2 ->aH2
//   phase B: L1 combine h1(k)->aH1[buf]  | L2 MFMA G2(k-1)->pD2
// MFMA and combine-VALU co-schedule (m114). A-reads 64->48 b128/CU/step.
// Chained MFMA accumulators (no x+y adds). B-frags in a union array so
// L1/L2 paths share registers (~230 VGPR, fits (512,2)).
// fp32 accuracy via bf16 hi+lo 3-product split.

#define TT 512
#define HH 64
#define BT 8

typedef __attribute__((ext_vector_type(8))) short short8;
typedef __attribute__((ext_vector_type(4))) float f32x4;

#define MFMA16 __builtin_amdgcn_mfma_f32_16x16x32_bf16

__device__ __forceinline__ float sigm(float x) {
    return __builtin_amdgcn_rcpf(1.f + __expf(-x));
}
__device__ __forceinline__ float tanh_f(float x) {
    float xc = fminf(fmaxf(x, -15.f), 15.f);
    float e = __expf(2.f * xc);
    return (e - 1.f) * __builtin_amdgcn_rcpf(e + 1.f);
}
__device__ __forceinline__ void cvt8(const float* p, short8& hi, short8& lo) {
    #pragma unroll
    for (int i = 0; i < 8; ++i) {
        float v = p[i];
        unsigned short h = (unsigned short)(__float_as_uint(v) >> 16);
        float r = v - __uint_as_float(((unsigned)h) << 16);
        unsigned short l = (unsigned short)(__float_as_uint(r) >> 16);
        hi[i] = (short)h;
        lo[i] = (short)l;
    }
}
__device__ __forceinline__ void split1(float v, unsigned short& h, unsigned short& l) {
    h = (unsigned short)(__float_as_uint(v) >> 16);
    float r = v - __uint_as_float(((unsigned)h) << 16);
    l = (unsigned short)(__float_as_uint(r) >> 16);
}
__device__ __forceinline__ float gate4(float pi, float pf, float pg, float po, float& c) {
    float gi = sigm(pi), gf = sigm(pf), gg = tanh_f(pg), go = sigm(po);
    c = fmaf(gf, c, gi * gg);
    return go * tanh_f(c);
}

__global__ __launch_bounds__(512, 2) void lstm_mfma(
    const float* __restrict__ x,
    const float* __restrict__ Wih0, const float* __restrict__ Whh0,
    const float* __restrict__ bih0, const float* __restrict__ bhh0,
    const float* __restrict__ Wih1, const float* __restrict__ Whh1,
    const float* __restrict__ bih1, const float* __restrict__ bhh1,
    const float* __restrict__ fcW, const float* __restrict__ fcb,
    float* __restrict__ out)
{
    __shared__ float xs[BT][TT + 1];                   // 16.4 KB
    __shared__ __align__(16) float pD1[256][20];       // 20 KB  G1 preacts
    __shared__ __align__(16) float pD2[256][20];       // 20 KB  G2 preacts
    __shared__ __align__(16) short aH1[2][2][2][64][8];// 8 KB [buf][kt][hi/lo][row][e]
    __shared__ __align__(16) short aH2[2][2][64][8];   // 4 KB [kt][hi/lo][row][e]
    __shared__ float hF[BT][HH + 1];
    __shared__ float fcw_s[HH];

    const int t    = threadIdx.x;
    const int lane = t & 63;
    const int w    = t >> 6;          // wave 0..7
    const bool isL1 = (w < 4);
    const int wv   = w & 3;           // group-local wave
    const int ntb  = wv * 64;         // column base (4 N-tiles of 16)
    const int b0   = blockIdx.x * BT;

    // ---- stage x (coalesced rows); zero A-frag buffers ----
    for (int i = t; i < BT * TT; i += 512)
        xs[i >> 9][i & (TT - 1)] = x[(size_t)(b0 + (i >> 9)) * TT + (i & (TT - 1))];
    {
        int* z1 = (int*)aH1;
        for (int i = t; i < 2048; i += 512) z1[i] = 0;
        int* z2 = (int*)aH2;
        for (int i = t; i < 1024; i += 512) z2[i] = 0;
    }
    if (t < HH) fcw_s[t] = fcW[t];

    // ---- persistent B fragments (union across groups): 32 short8 = 128 regs ----
    // L1-wave: kt0..1 from Whh0 (G1).  L2-wave: kt0..1 Wih1, kt2..3 Whh1 (G2).
    short8 bfh[4][4], bfl[4][4];      // [kt][nt]
    {
        const int n_lo = lane & 15;
        const int k8   = (lane >> 4) * 8;
        #pragma unroll
        for (int nt = 0; nt < 4; ++nt) {
            const int col = ntb + nt * 16 + n_lo;
            if (isL1) {
                cvt8(Whh0 + col * HH +      k8, bfh[0][nt], bfl[0][nt]);
                cvt8(Whh0 + col * HH + 32 + k8, bfh[1][nt], bfl[1][nt]);
            } else {
                cvt8(Wih1 + col * HH +      k8, bfh[0][nt], bfl[0][nt]);
                cvt8(Wih1 + col * HH + 32 + k8, bfh[1][nt], bfl[1][nt]);
                cvt8(Whh1 + col * HH +      k8, bfh[2][nt], bfl[2][nt]);
                cvt8(Whh1 + col * HH + 32 + k8, bfh[3][nt], bfl[3][nt]);
            }
        }
    }

    // ---- combine constants: group-lane gl owns pairs (cb,cj0),(cb,cj1) ----
    const int gl  = wv * 64 + lane;   // 0..255 within group
    const int cb  = gl & 7;
    const int cj0 = gl >> 3;          // 0..31
    const int cj1 = cj0 + 32;
    const int sla = cb + ((cj0 >> 3) & 3) * 16;
    const int sel = cj0 & 7;
    float wA[4], wB[4], bA[4], bB[4];
    #pragma unroll
    for (int g = 0; g < 4; ++g) {
        if (isL1) {
            wA[g] = Wih0[g * 64 + cj0];
            wB[g] = Wih0[g * 64 + cj1];
            bA[g] = bih0[g * 64 + cj0] + bhh0[g * 64 + cj0];
            bB[g] = bih0[g * 64 + cj1] + bhh0[g * 64 + cj1];
        } else {
            wA[g] = 0.f; wB[g] = 0.f;
            bA[g] = bih1[g * 64 + cj0] + bhh1[g * 64 + cj0];
            bB[g] = bih1[g * 64 + cj1] + bhh1[g * 64 + cj1];
        }
    }
    float cA = 0.f, cB = 0.f;
    __syncthreads();

    #pragma unroll 2
    for (int k = 0; k < TT; ++k) {
        const int p = k & 1, pn = p ^ 1;

        // ======== phase A ========
        if (isL1) {
            // MFMA G1(k) = Whh0 * h1(k-1)
            short8 a0h = *(const short8*)&aH1[p][0][0][lane][0];
            short8 a0l = *(const short8*)&aH1[p][0][1][lane][0];
            short8 a1h = *(const short8*)&aH1[p][1][0][lane][0];
            short8 a1l = *(const short8*)&aH1[p][1][1][lane][0];
            #pragma unroll
            for (int nt = 0; nt < 4; ++nt) {
                f32x4 acc = {0.f, 0.f, 0.f, 0.f};
                acc = MFMA16(a0h, bfh[0][nt], acc, 0, 0, 0);
                acc = MFMA16(a0h, bfl[0][nt], acc, 0, 0, 0);
                acc = MFMA16(a0l, bfh[0][nt], acc, 0, 0, 0);
                acc = MFMA16(a1h, bfh[1][nt], acc, 0, 0, 0);
                acc = MFMA16(a1h, bfl[1][nt], acc, 0, 0, 0);
                acc = MFMA16(a1l, bfh[1][nt], acc, 0, 0, 0);
                *(f32x4*)&pD1[ntb + nt * 16 + (lane & 15)][(lane >> 4) * 4] = acc;
            }
        } else if (k >= 2) {
            // combine h2(k-2) from pD2
            float h2a = gate4(pD2[cj0][cb] + bA[0],       pD2[64 + cj0][cb] + bA[1],
                              pD2[128 + cj0][cb] + bA[2], pD2[192 + cj0][cb] + bA[3], cA);
            float h2b = gate4(pD2[cj1][cb] + bB[0],       pD2[64 + cj1][cb] + bB[1],
                              pD2[128 + cj1][cb] + bB[2], pD2[192 + cj1][cb] + bB[3], cB);
            unsigned short h, l;
            split1(h2a, h, l);
            aH2[0][0][sla][sel] = (short)h;
            aH2[0][1][sla][sel] = (short)l;
            split1(h2b, h, l);
            aH2[1][0][sla][sel] = (short)h;
            aH2[1][1][sla][sel] = (short)l;
        }
        __syncthreads();

        // ======== phase B ========
        if (isL1) {
            // combine h1(k) from pD1 (+ x term)
            float xb = xs[cb][k];
            float h1a = gate4(pD1[cj0][cb]       + fmaf(wA[0], xb, bA[0]),
                              pD1[64 + cj0][cb]  + fmaf(wA[1], xb, bA[1]),
                              pD1[128 + cj0][cb] + fmaf(wA[2], xb, bA[2]),
                              pD1[192 + cj0][cb] + fmaf(wA[3], xb, bA[3]), cA);
            float h1b = gate4(pD1[cj1][cb]       + fmaf(wB[0], xb, bB[0]),
                              pD1[64 + cj1][cb]  + fmaf(wB[1], xb, bB[1]),
                              pD1[128 + cj1][cb] + fmaf(wB[2], xb, bB[2]),
                              pD1[192 + cj1][cb] + fmaf(wB[3], xb, bB[3]), cB);
            unsigned short h, l;
            split1(h1a, h, l);
            aH1[pn][0][0][sla][sel] = (short)h;
            aH1[pn][0][1][sla][sel] = (short)l;
            split1(h1b, h, l);
            aH1[pn][1][0][sla][sel] = (short)h;
            aH1[pn][1][1][sla][sel] = (short)l;
        } else {
            // MFMA G2(k-1) = Wih1*h1(k-1) + Whh1*h2(k-2)   (k=0: junk, ignored)
            short8 a0h = *(const short8*)&aH1[p][0][0][lane][0];
            short8 a0l = *(const short8*)&aH1[p][0][1][lane][0];
            short8 a1h = *(const short8*)&aH1[p][1][0][lane][0];
            short8 a1l = *(const short8*)&aH1[p][1][1][lane][0];
            short8 a2h = *(const short8*)&aH2[0][0][lane][0];
            short8 a2l = *(const short8*)&aH2[0][1][lane][0];
            short8 a3h = *(const short8*)&aH2[1][0][lane][0];
            short8 a3l = *(const short8*)&aH2[1][1][lane][0];
            #pragma unroll
            for (int nt = 0; nt < 4; ++nt) {
                f32x4 acc = {0.f, 0.f, 0.f, 0.f};
                acc = MFMA16(a0h, bfh[0][nt], acc, 0, 0, 0);
                acc = MFMA16(a0h, bfl[0][nt], acc, 0, 0, 0);
                acc = MFMA16(a0l, bfh[0][nt], acc, 0, 0, 0);
                acc = MFMA16(a1h, bfh[1][nt], acc, 0, 0, 0);
                acc = MFMA16(a1h, bfl[1][nt], acc, 0, 0, 0);
                acc = MFMA16(a1l, bfh[1][nt], acc, 0, 0, 0);
                acc = MFMA16(a2h, bfh[2][nt], acc, 0, 0, 0);
                acc = MFMA16(a2h, bfl[2][nt], acc, 0, 0, 0);
                acc = MFMA16(a2l, bfh[2][nt], acc, 0, 0, 0);
                acc = MFMA16(a3h, bfh[3][nt], acc, 0, 0, 0);
                acc = MFMA16(a3h, bfl[3][nt], acc, 0, 0, 0);
                acc = MFMA16(a3l, bfh[3][nt], acc, 0, 0, 0);
                *(f32x4*)&pD2[ntb + nt * 16 + (lane & 15)][(lane >> 4) * 4] = acc;
            }
        }
        __syncthreads();
    }

    // ---- epilogue: finish layer-2 skew (h2(TT-2), then h2(TT-1)) ----
    if (!isL1) {
        // combine h2(TT-2) from pD2 (written at phase B of k=TT-1)
        float h2a = gate4(pD2[cj0][cb] + bA[0],       pD2[64 + cj0][cb] + bA[1],
                          pD2[128 + cj0][cb] + bA[2], pD2[192 + cj0][cb] + bA[3], cA);
        float h2b = gate4(pD2[cj1][cb] + bB[0],       pD2[64 + cj1][cb] + bB[1],
                          pD2[128 + cj1][cb] + bB[2], pD2[192 + cj1][cb] + bB[3], cB);
        unsigned short h, l;
        split1(h2a, h, l);
        aH2[0][0][sla][sel] = (short)h;
        aH2[0][1][sla][sel] = (short)l;
        split1(h2b, h, l);
        aH2[1][0][sla][sel] = (short)h;
        aH2[1][1][sla][sel] = (short)l;
    }
    __syncthreads();
    if (!isL1) {
        // MFMA G2(TT-1): h1(TT-1) in aH1[0] (TT even), h2(TT-2) in aH2
        short8 a0h = *(const short8*)&aH1[0][0][0][lane][0];
        short8 a0l = *(const short8*)&aH1[0][0][1][lane][0];
        short8 a1h = *(const short8*)&aH1[0][1][0][lane][0];
        short8 a1l = *(const short8*)&aH1[0][1][1][lane][0];
        short8 a2h = *(const short8*)&aH2[0][0][lane][0];
        short8 a2l = *(const short8*)&aH2[0][1][lane][0];
        short8 a3h = *(const short8*)&aH2[1][0][lane][0];
        short8 a3l = *(const short8*)&aH2[1][1][lane][0];
        #pragma unroll
        for (int nt = 0; nt < 4; ++nt) {
            f32x4 acc = {0.f, 0.f, 0.f, 0.f};
            acc = MFMA16(a0h, bfh[0][nt], acc, 0, 0, 0);
            acc = MFMA16(a0h, bfl[0][nt], acc, 0, 0, 0);
            acc = MFMA16(a0l, bfh[0][nt], acc, 0, 0, 0);
            acc = MFMA16(a1h, bfh[1][nt], acc, 0, 0, 0);
            acc = MFMA16(a1h, bfl[1][nt], acc, 0, 0, 0);
            acc = MFMA16(a1l, bfh[1][nt], acc, 0, 0, 0);
            acc = MFMA16(a2h, bfh[2][nt], acc, 0, 0, 0);
            acc = MFMA16(a2h, bfl[2][nt], acc, 0, 0, 0);
            acc = MFMA16(a2l, bfh[2][nt], acc, 0, 0, 0);
            acc = MFMA16(a3h, bfh[3][nt], acc, 0, 0, 0);
            acc = MFMA16(a3h, bfl[3][nt], acc, 0, 0, 0);
            acc = MFMA16(a3l, bfh[3][nt], acc, 0, 0, 0);
            *(f32x4*)&pD2[ntb + nt * 16 + (lane & 15)][(lane >> 4) * 4] = acc;
        }
    }
    __syncthreads();
    if (!isL1) {
        // combine h2(TT-1) -> hF
        float h2a = gate4(pD2[cj0][cb] + bA[0],       pD2[64 + cj0][cb] + bA[1],
                          pD2[128 + cj0][cb] + bA[2], pD2[192 + cj0][cb] + bA[3], cA);
        float h2b = gate4(pD2[cj1][cb] + bB[0],       pD2[64 + cj1][cb] + bB[1],
                          pD2[128 + cj1][cb] + bB[2], pD2[192 + cj1][cb] + bB[3], cB);
        hF[cb][cj0] = h2a;
        hF[cb][cj1] = h2b;
    }
    __syncthreads();

    // ---- final FC: out[b] = fcW . h2(TT-1)[b] + fcb ----
    if (t < BT) {
        float s = fcb[0];
        #pragma unroll 8
        for (int j = 0; j < HH; ++j)
            s = fmaf(hF[t][j], fcw_s[j], s);
        out[b0 + t] = s;
    }
}

extern "C" void kernel_launch(void* const* d_in, const int* in_sizes, int n_in,
                              void* d_out, int out_size, void* d_ws, size_t ws_size,
                              hipStream_t stream) {
    const float* x    = (const float*)d_in[0];
    const float* Wih0 = (const float*)d_in[1];
    const float* Whh0 = (const float*)d_in[2];
    const float* bih0 = (const float*)d_in[3];
    const float* bhh0 = (const float*)d_in[4];
    const float* Wih1 = (const float*)d_in[5];
    const float* Whh1 = (const float*)d_in[6];
    const float* bih1 = (const float*)d_in[7];
    const float* bhh1 = (const float*)d_in[8];
    const float* fcW  = (const float*)d_in[9];
    const float* fcb  = (const float*)d_in[10];
    float* out = (float*)d_out;

    lstm_mfma<<<dim3(2048 / BT), dim3(512), 0, stream>>>(
        x, Wih0, Whh0, bih0, bhh0, Wih1, Whh1, bih1, bhh1, fcW, fcb, out);
}